// Round 1
// 575.730 us; speedup vs baseline: 1.0117x; 1.0117x over previous
//
#include <hip/hip_runtime.h>
#include <math.h>

#define N_TOK 16384
#define DDIM  4096
#define NEXP  64
#define TM    32            // tokens per block
#define NSL   8             // K slices per block (one per wave-pair)
#define KSL   (DDIM / NSL)  // 512 columns per slice
#define LSTR  68            // LDS logit row stride
#define TAU   1e-3f         // near-tie refine threshold (split-bf16 noise ~1e-5)

typedef __attribute__((ext_vector_type(8))) short bf16x8;
typedef __attribute__((ext_vector_type(4))) float f32x4;

// Split 8 consecutive fp32 into hi/lo bf16 (truncation split: x = hi + lo + eps,
// |lo| <= 2^-8|x|, |eps| <= 2^-16|x|; eps zero-mean vs random w).
__device__ __forceinline__ void split8(f32x4 v0, f32x4 v1, bf16x8& hi, bf16x8& lo) {
    float f[8];
    *(f32x4*)&f[0] = v0;  *(f32x4*)&f[4] = v1;
    #pragma unroll
    for (int i = 0; i < 8; ++i) {
        unsigned u  = __float_as_uint(f[i]);
        unsigned uh = u & 0xFFFF0000u;
        float    rf = f[i] - __uint_as_float(uh);
        hi[i] = (short)(u >> 16);
        lo[i] = (short)(__float_as_uint(rf) >> 16);
    }
}

// 1024 threads = 16 waves: 2 token-groups x 8 K-slices. VGPR must stay <=64 so
// 2 blocks/CU x 16 waves = 32 waves/CU (occupancy was the bottleneck at 4 waves).
__global__ __launch_bounds__(1024, 8) void topk_gate_kernel(
    const float* __restrict__ x, const float* __restrict__ W,
    float* __restrict__ out)
{
    __shared__ float  Lgh[NSL][TM][LSTR];    // per-K-slice logits (~70 KB)
    __shared__ int    top_i[TM * 2];
    __shared__ float  top_w[TM * 2];
    __shared__ int    nflag;
    __shared__ int    flist[TM];
    __shared__ double red[512];
    __shared__ double lgd[NEXP];
    __shared__ int    rbi[2];
    __shared__ float  rbw[2];

    const int tid  = threadIdx.x;
    const int lane = tid & 63;
    const int w    = tid >> 6;           // wave 0..15
    const int tg   = w & 1;              // token group (16 tokens)
    const int ks   = w >> 1;             // K slice 0..7
    const int block_tok = blockIdx.x * TM;

    const int r16  = lane & 15;          // row within 16 (token / expert)
    const int koct = lane >> 4;          // k-octet 0..3

    // A: x[block_tok + tg*16 + r16][ks*KSL + koct*8 + kb + (0..7)]
    const float* xp = x + (size_t)(block_tok + tg * 16 + r16) * DDIM
                        + ks * KSL + koct * 8;
    // B tile t: W[t*16 + r16][ks*KSL + koct*8 + kb + (0..7)]
    const float* wp0 = W + (size_t)r16 * DDIM + ks * KSL + koct * 8;

    f32x4 acc[4];
    #pragma unroll
    for (int t = 0; t < 4; ++t) acc[t] = (f32x4){0.f, 0.f, 0.f, 0.f};

    #pragma unroll 2
    for (int kb = 0; kb < KSL; kb += 32) {
        f32x4 a0 = *(const f32x4*)(xp + kb);
        f32x4 a1 = *(const f32x4*)(xp + kb + 4);
        bf16x8 ah, al;
        split8(a0, a1, ah, al);
        #pragma unroll
        for (int t = 0; t < 4; ++t) {
            const float* wp = wp0 + (size_t)t * 16 * DDIM + kb;
            f32x4 b0 = *(const f32x4*)(wp);
            f32x4 b1 = *(const f32x4*)(wp + 4);
            bf16x8 bh, bl;
            split8(b0, b1, bh, bl);
            acc[t] = __builtin_amdgcn_mfma_f32_16x16x32_bf16(ah, bh, acc[t], 0, 0, 0);
            acc[t] = __builtin_amdgcn_mfma_f32_16x16x32_bf16(ah, bl, acc[t], 0, 0, 0);
            acc[t] = __builtin_amdgcn_mfma_f32_16x16x32_bf16(al, bh, acc[t], 0, 0, 0);
        }
    }

    // C/D layout (m89-verified): col = lane&15 (expert), row = (lane>>4)*4 + reg (token)
    #pragma unroll
    for (int t = 0; t < 4; ++t)
        #pragma unroll
        for (int r = 0; r < 4; ++r)
            Lgh[ks][tg * 16 + koct * 4 + r][t * 16 + r16] = acc[t][r];
    if (tid == 0) nflag = 0;
    __syncthreads();

    // ---- parallel combine of the 8 K-slices into Lgh[0] (float4, 512 thr) ----
    if (tid < 512) {
        const int tok = tid >> 4;            // 0..31
        const int e4  = (tid & 15) * 4;      // 0,4,..,60
        float4 s = *(const float4*)&Lgh[0][tok][e4];
        #pragma unroll
        for (int h = 1; h < NSL; ++h) {
            float4 v = *(const float4*)&Lgh[h][tok][e4];
            s.x += v.x; s.y += v.y; s.z += v.z; s.w += v.w;
        }
        *(float4*)&Lgh[0][tok][e4] = s;
    }
    __syncthreads();

    // ---- top-3 scan + 2-way softmax + near-tie flagging ----
    if (tid < TM) {
        float m1 = -INFINITY, m2 = -INFINITY, m3 = -INFINITY;
        int i1 = 0, i2 = 0;
        for (int e = 0; e < NEXP; ++e) {
            float v = Lgh[0][tid][e];
            if (v > m1)      { m3 = m2; m2 = m1; i2 = i1; m1 = v; i1 = e; }
            else if (v > m2) { m3 = m2; m2 = v; i2 = e; }
            else if (v > m3) { m3 = v; }
        }
        float d  = expf(m2 - m1);
        float rn = 1.0f / (1.0f + d);
        top_i[tid * 2 + 0] = i1;  top_i[tid * 2 + 1] = i2;
        top_w[tid * 2 + 0] = rn;  top_w[tid * 2 + 1] = d * rn;
        float2* oi = (float2*)(out + (size_t)N_TOK * NEXP);
        oi[block_tok + tid] = make_float2((float)i1, (float)i2);
        if ((m1 - m2 < TAU) || (m2 - m3 < TAU)) {
            int p = atomicAdd(&nflag, 1);
            flist[p] = tid;
        }
    }
    __syncthreads();

    // ---- dense weight scatter: 32 tokens x 64 experts, float4 coalesced ----
    if (tid < 512) {
        float4* ow = (float4*)(out + (size_t)block_tok * NEXP);
        const int tok = tid >> 4;
        const int e4  = (tid & 15) * 4;
        int a1 = top_i[tok * 2], a2 = top_i[tok * 2 + 1];
        float v1 = top_w[tok * 2], v2 = top_w[tok * 2 + 1];
        float4 v; float* vp = (float*)&v;
        #pragma unroll
        for (int q = 0; q < 4; ++q) {
            int e = e4 + q;
            vp[q] = (e == a1) ? v1 : ((e == a2) ? v2 : 0.0f);
        }
        ow[tid] = v;
    }
    __syncthreads();

    // ---- in-block fp64 re-resolution of flagged tokens (expected ~0.07/block) ----
    const int fn = nflag;
    for (int f = 0; f < fn; ++f) {
        const int tok = block_tok + flist[f];
        if (tid < 512) {
            const int e = tid & 63, q = tid >> 6;   // q: 0..7
            const float* wr = W + (size_t)e * DDIM + q * (DDIM / 8);
            const float* xr = x + (size_t)tok * DDIM + q * (DDIM / 8);
            double p = 0.0;
            for (int k = 0; k < DDIM / 8; k += 4) {
                float4 wv = *(const float4*)(wr + k);
                float4 xv = *(const float4*)(xr + k);
                p += (double)xv.x * (double)wv.x;
                p += (double)xv.y * (double)wv.y;
                p += (double)xv.z * (double)wv.z;
                p += (double)xv.w * (double)wv.w;
            }
            red[tid] = p;
        }
        __syncthreads();
        if (tid < 64) {
            double s = 0.0;
            #pragma unroll
            for (int j = 0; j < 8; ++j) s += red[tid + 64 * j];
            lgd[tid] = s;
        }
        __syncthreads();

        if (tid == 0) {
            double m1 = -INFINITY, m2 = -INFINITY;
            int i1 = 0, i2 = 0;
            for (int ee = 0; ee < NEXP; ++ee) {
                double v = lgd[ee];
                if (v > m1)      { m2 = m1; i2 = i1; m1 = v; i1 = ee; }
                else if (v > m2) { m2 = v; i2 = ee; }
            }
            double d  = exp(m2 - m1);
            double rn = 1.0 / (1.0 + d);
            rbi[0] = i1; rbi[1] = i2;
            rbw[0] = (float)rn; rbw[1] = (float)(d * rn);
            float2* oi = (float2*)(out + (size_t)N_TOK * NEXP);
            oi[tok] = make_float2((float)i1, (float)i2);
        }
        __syncthreads();

        if (tid < 16) {
            float4 v = make_float4(0.f, 0.f, 0.f, 0.f);
            float* vp = (float*)&v;
            #pragma unroll
            for (int qq = 0; qq < 4; ++qq) {
                int ee = tid * 4 + qq;
                if (ee == rbi[0]) vp[qq] = rbw[0];
                else if (ee == rbi[1]) vp[qq] = rbw[1];
            }
            ((float4*)(out + (size_t)tok * NEXP))[tid] = v;
        }
        __syncthreads();
    }
}

extern "C" void kernel_launch(void* const* d_in, const int* in_sizes, int n_in,
                              void* d_out, int out_size, void* d_ws, size_t ws_size,
                              hipStream_t stream) {
    const float* x = (const float*)d_in[0];   // [16384, 4096] fp32
    const float* W = (const float*)d_in[1];   // [64, 4096] fp32
    float* out = (float*)d_out;               // weights [16384*64] then indices [16384*2]
    (void)in_sizes; (void)n_in; (void)d_ws; (void)ws_size; (void)out_size;

    hipLaunchKernelGGL(topk_gate_kernel, dim3(N_TOK / TM), dim3(1024), 0, stream,
                       x, W, out);
}

// Round 2
// 549.504 us; speedup vs baseline: 1.0600x; 1.0477x over previous
//
#include <hip/hip_runtime.h>
#include <math.h>

#define N_TOK 16384
#define DDIM  4096
#define NEXP  64
#define TM    64             // tokens per block
#define BK    128            // K columns staged per step
#define NSTEP (DDIM / BK)    // 32
#define LSTR  68             // LDS logit row stride (68*4B = 272B, 16B-aligned rows)
#define TAU   1e-3f          // near-tie refine threshold (split-bf16 noise ~1e-5)

static_assert(NSTEP % 2 == 0, "pipeline assumes even step count");

typedef __attribute__((ext_vector_type(8))) short bf16x8;
typedef __attribute__((ext_vector_type(4))) float f32x4;

// Split 8 consecutive fp32 into hi/lo bf16 (truncation split: x = hi + lo + eps).
__device__ __forceinline__ void split8(f32x4 v0, f32x4 v1, bf16x8& hi, bf16x8& lo) {
    float f[8];
    *(f32x4*)&f[0] = v0;  *(f32x4*)&f[4] = v1;
    #pragma unroll
    for (int i = 0; i < 8; ++i) {
        unsigned u  = __float_as_uint(f[i]);
        unsigned uh = u & 0xFFFF0000u;
        float    rf = f[i] - __uint_as_float(uh);
        hi[i] = (short)(u >> 16);
        lo[i] = (short)(__float_as_uint(rf) >> 16);
    }
}

// async global->LDS, 16B per lane. LDS dest = wave-uniform base + lane*16 (linear).
__device__ __forceinline__ void gl2lds16(const void* g, void* l) {
    __builtin_amdgcn_global_load_lds(
        (const __attribute__((address_space(1))) unsigned int*)g,
        (__attribute__((address_space(3))) unsigned int*)l,
        16, 0, 0);
}

// Buffer layout per phase b (b=0,1): sraw + b*65536:
//   [0,      32768)  x-tile  [64 rows][128 f32], row r swizzled: byte^=(r&7)<<4
//   [32768,  65536)  W-tile  [64 rows][128 f32], same swizzle
// Epilogue aliases: logits Lg[2][64][68] f32 at sraw+0; red[512] f64 at sraw+65536.
__global__ __launch_bounds__(512, 2) void topk_gate_kernel(
    const float* __restrict__ x, const float* __restrict__ W,
    float* __restrict__ out)
{
    __shared__ __align__(16) char sraw[2 * 65536];
    __shared__ int    top_i[TM * 2];
    __shared__ float  top_w[TM * 2];
    __shared__ int    nflag;
    __shared__ int    flist[TM];
    __shared__ double lgd[NEXP];
    __shared__ int    rbi[2];
    __shared__ float  rbw[2];

    const int tid  = threadIdx.x;
    const int lane = tid & 63;
    const int w    = tid >> 6;           // wave 0..7
    const int tt   = w & 3;              // token tile (16 tokens)
    const int h    = w >> 2;             // K-half of each BK step (sub-iters 2h, 2h+1)
    const int block_tok = blockIdx.x * TM;

    const int r16  = lane & 15;          // fragment row (token / expert)
    const int koct = lane >> 4;          // k-octet 0..3

    // ---- staging source pointers: issue q=w*4+j stages rows {2q, 2q+1} ----
    // global source is per-lane; pre-apply inverse swizzle so linear LDS dest
    // lands swizzled (rule #21: swizzle both sides or neither).
    const int l31 = lane & 31;
    const int qbase = w * 4;
    const char *xs0, *xs1, *xs2, *xs3, *ws0, *ws1, *ws2, *ws3;
    {
        int r0 = (qbase + 0) * 2 + (lane >> 5);
        int r1 = (qbase + 1) * 2 + (lane >> 5);
        int r2 = (qbase + 2) * 2 + (lane >> 5);
        int r3 = (qbase + 3) * 2 + (lane >> 5);
        int s0 = (l31 * 16) ^ ((r0 & 7) << 4);
        int s1 = (l31 * 16) ^ ((r1 & 7) << 4);
        int s2 = (l31 * 16) ^ ((r2 & 7) << 4);
        int s3 = (l31 * 16) ^ ((r3 & 7) << 4);
        xs0 = (const char*)x + (size_t)(block_tok + r0) * (DDIM * 4) + s0;
        xs1 = (const char*)x + (size_t)(block_tok + r1) * (DDIM * 4) + s1;
        xs2 = (const char*)x + (size_t)(block_tok + r2) * (DDIM * 4) + s2;
        xs3 = (const char*)x + (size_t)(block_tok + r3) * (DDIM * 4) + s3;
        ws0 = (const char*)W + (size_t)r0 * (DDIM * 4) + s0;
        ws1 = (const char*)W + (size_t)r1 * (DDIM * 4) + s1;
        ws2 = (const char*)W + (size_t)r2 * (DDIM * 4) + s2;
        ws3 = (const char*)W + (size_t)r3 * (DDIM * 4) + s3;
    }

#define STAGE(B, ST) do {                                                   \
    size_t _o = (size_t)(ST) * 512;                                         \
    char*  _d = sraw + (B) * 65536 + qbase * 1024;                          \
    gl2lds16(xs0 + _o, _d);          gl2lds16(ws0 + _o, _d + 32768);        \
    gl2lds16(xs1 + _o, _d + 1024);   gl2lds16(ws1 + _o, _d + 33792);        \
    gl2lds16(xs2 + _o, _d + 2048);   gl2lds16(ws2 + _o, _d + 34816);        \
    gl2lds16(xs3 + _o, _d + 3072);   gl2lds16(ws3 + _o, _d + 35840);        \
} while (0)

    // fragment read swizzle constants (row&7 == r16&7 for both x and W tiles)
    const int Q  = (r16 & 7) << 4;
    const int pa = (koct * 32) ^ Q;          // first 16B of the 32B fragment
    const int pb = (koct * 32 + 16) ^ Q;     // second 16B

    f32x4 acc[4];
    #pragma unroll
    for (int t = 0; t < 4; ++t) acc[t] = (f32x4){0.f, 0.f, 0.f, 0.f};

#define COMPUTE(B) do {                                                     \
    const char* _xb = sraw + (B) * 65536 + (tt * 16 + r16) * 512;           \
    const char* _wb = sraw + (B) * 65536 + 32768 + r16 * 512;               \
    _Pragma("unroll")                                                       \
    for (int ss = 0; ss < 2; ++ss) {                                        \
        const int sofs = (2 * h + ss) * 128;                                \
        f32x4 a0 = *(const f32x4*)(_xb + sofs + pa);                        \
        f32x4 a1 = *(const f32x4*)(_xb + sofs + pb);                        \
        bf16x8 ah, al;  split8(a0, a1, ah, al);                             \
        _Pragma("unroll")                                                   \
        for (int t = 0; t < 4; ++t) {                                       \
            const char* _wt = _wb + t * 8192;                               \
            f32x4 b0 = *(const f32x4*)(_wt + sofs + pa);                    \
            f32x4 b1 = *(const f32x4*)(_wt + sofs + pb);                    \
            bf16x8 bh, bl;  split8(b0, b1, bh, bl);                         \
            acc[t] = __builtin_amdgcn_mfma_f32_16x16x32_bf16(ah, bh, acc[t], 0, 0, 0); \
            acc[t] = __builtin_amdgcn_mfma_f32_16x16x32_bf16(ah, bl, acc[t], 0, 0, 0); \
            acc[t] = __builtin_amdgcn_mfma_f32_16x16x32_bf16(al, bh, acc[t], 0, 0, 0); \
        }                                                                   \
    }                                                                       \
} while (0)

    // ---- 2-phase pipelined K loop (T3 minimum: stage next, compute cur) ----
    STAGE(0, 0);
    __syncthreads();
    #pragma unroll 1
    for (int st = 0; st < NSTEP; st += 2) {
        if (st + 1 < NSTEP) STAGE(1, st + 1);
        COMPUTE(0);
        __syncthreads();
        if (st + 2 < NSTEP) STAGE(0, st + 2);
        COMPUTE(1);
        __syncthreads();
    }

    // ---- epilogue: logits into LDS (aliases staging buffers, barrier passed) ----
    float* Lg = (float*)sraw;            // [2][64][LSTR]
    #pragma unroll
    for (int t = 0; t < 4; ++t)
        #pragma unroll
        for (int r = 0; r < 4; ++r)
            Lg[(h * 64 + tt * 16 + koct * 4 + r) * LSTR + t * 16 + r16] = acc[t][r];
    if (tid == 0) nflag = 0;
    __syncthreads();

    // combine the two K-halves: 512 threads x 8 experts each
    {
        const int tok = tid >> 3;
        const int e8  = (tid & 7) * 8;
        float4 s0 = *(float4*)&Lg[tok * LSTR + e8];
        float4 s1 = *(float4*)&Lg[tok * LSTR + e8 + 4];
        float4 u0 = *(float4*)&Lg[(64 + tok) * LSTR + e8];
        float4 u1 = *(float4*)&Lg[(64 + tok) * LSTR + e8 + 4];
        s0.x += u0.x; s0.y += u0.y; s0.z += u0.z; s0.w += u0.w;
        s1.x += u1.x; s1.y += u1.y; s1.z += u1.z; s1.w += u1.w;
        *(float4*)&Lg[tok * LSTR + e8]     = s0;
        *(float4*)&Lg[tok * LSTR + e8 + 4] = s1;
    }
    __syncthreads();

    // ---- top-3 scan + 2-way softmax + near-tie flagging (one thread/token) ----
    if (tid < TM) {
        float m1 = -INFINITY, m2 = -INFINITY, m3 = -INFINITY;
        int i1 = 0, i2 = 0;
        for (int e = 0; e < NEXP; ++e) {
            float v = Lg[tid * LSTR + e];
            if (v > m1)      { m3 = m2; m2 = m1; i2 = i1; m1 = v; i1 = e; }
            else if (v > m2) { m3 = m2; m2 = v; i2 = e; }
            else if (v > m3) { m3 = v; }
        }
        float d  = expf(m2 - m1);
        float rn = 1.0f / (1.0f + d);
        top_i[tid * 2 + 0] = i1;  top_i[tid * 2 + 1] = i2;
        top_w[tid * 2 + 0] = rn;  top_w[tid * 2 + 1] = d * rn;
        float2* oi = (float2*)(out + (size_t)N_TOK * NEXP);
        oi[block_tok + tid] = make_float2((float)i1, (float)i2);
        if ((m1 - m2 < TAU) || (m2 - m3 < TAU)) {
            int p = atomicAdd(&nflag, 1);
            flist[p] = tid;
        }
    }
    __syncthreads();

    // ---- dense weight scatter: 64 tokens x 64 experts, float4 coalesced ----
    {
        float4* ow = (float4*)(out + (size_t)block_tok * NEXP);
        #pragma unroll
        for (int jj = 0; jj < 2; ++jj) {
            int flat = tid + jj * 512;       // 0..1023
            int tok  = flat >> 4;
            int e4   = (flat & 15) * 4;
            int a1 = top_i[tok * 2], a2 = top_i[tok * 2 + 1];
            float v1 = top_w[tok * 2], v2 = top_w[tok * 2 + 1];
            float4 v; float* vp = (float*)&v;
            #pragma unroll
            for (int q = 0; q < 4; ++q) {
                int e = e4 + q;
                vp[q] = (e == a1) ? v1 : ((e == a2) ? v2 : 0.0f);
            }
            ow[flat] = v;
        }
    }
    __syncthreads();

    // ---- in-block fp64 re-resolution of flagged tokens (~0.14/block) ----
    double* red = (double*)(sraw + 65536);   // aliases phase-1 buffer (synced)
    const int fn = nflag;
    for (int f = 0; f < fn; ++f) {
        const int tok = block_tok + flist[f];
        {
            const int e = tid & 63, q = tid >> 6;   // q: 0..7
            const float* wr = W + (size_t)e * DDIM + q * (DDIM / 8);
            const float* xr = x + (size_t)tok * DDIM + q * (DDIM / 8);
            double p = 0.0;
            for (int k = 0; k < DDIM / 8; k += 4) {
                float4 wv = *(const float4*)(wr + k);
                float4 xv = *(const float4*)(xr + k);
                p += (double)xv.x * (double)wv.x;
                p += (double)xv.y * (double)wv.y;
                p += (double)xv.z * (double)wv.z;
                p += (double)xv.w * (double)wv.w;
            }
            red[tid] = p;
        }
        __syncthreads();
        if (tid < 64) {
            double s = 0.0;
            #pragma unroll
            for (int j = 0; j < 8; ++j) s += red[tid + 64 * j];
            lgd[tid] = s;
        }
        __syncthreads();

        if (tid == 0) {
            double m1 = -INFINITY, m2 = -INFINITY;
            int i1 = 0, i2 = 0;
            for (int ee = 0; ee < NEXP; ++ee) {
                double v = lgd[ee];
                if (v > m1)      { m2 = m1; i2 = i1; m1 = v; i1 = ee; }
                else if (v > m2) { m2 = v; i2 = ee; }
            }
            double d  = exp(m2 - m1);
            double rn = 1.0 / (1.0 + d);
            rbi[0] = i1; rbi[1] = i2;
            rbw[0] = (float)rn; rbw[1] = (float)(d * rn);
            float2* oi = (float2*)(out + (size_t)N_TOK * NEXP);
            oi[tok] = make_float2((float)i1, (float)i2);
        }
        __syncthreads();

        if (tid < 16) {
            float4 v = make_float4(0.f, 0.f, 0.f, 0.f);
            float* vp = (float*)&v;
            #pragma unroll
            for (int qq = 0; qq < 4; ++qq) {
                int ee = tid * 4 + qq;
                if (ee == rbi[0]) vp[qq] = rbw[0];
                else if (ee == rbi[1]) vp[qq] = rbw[1];
            }
            ((float4*)(out + (size_t)tok * NEXP))[tid] = v;
        }
        __syncthreads();
    }
#undef STAGE
#undef COMPUTE
}

extern "C" void kernel_launch(void* const* d_in, const int* in_sizes, int n_in,
                              void* d_out, int out_size, void* d_ws, size_t ws_size,
                              hipStream_t stream) {
    const float* x = (const float*)d_in[0];   // [16384, 4096] fp32
    const float* W = (const float*)d_in[1];   // [64, 4096] fp32
    float* out = (float*)d_out;               // weights [16384*64] then indices [16384*2]
    (void)in_sizes; (void)n_in; (void)d_ws; (void)ws_size; (void)out_size;

    hipLaunchKernelGGL(topk_gate_kernel, dim3(N_TOK / TM), dim3(512), 0, stream,
                       x, W, out);
}

// Round 3
// 544.544 us; speedup vs baseline: 1.0696x; 1.0091x over previous
//
#include <hip/hip_runtime.h>
#include <math.h>

#define N_TOK 16384
#define DDIM  4096
#define NEXP  64
#define TM    32             // tokens per block
#define NQ    4              // K quarters (one consumer wave each)
#define KQ    (DDIM / NQ)    // 1024
#define BKQ   32             // cols per quarter per step
#define NSTEP (KQ / BKQ)     // 32 steps
#define LSTR  68             // LDS logit row stride
#define TAU   1e-3f          // near-tie refine threshold

typedef __attribute__((ext_vector_type(8))) short bf16x8;
typedef __attribute__((ext_vector_type(4))) float f32x4;

// Split 8 consecutive fp32 into hi/lo bf16 (truncation split: x = hi + lo + eps).
__device__ __forceinline__ void split8(f32x4 v0, f32x4 v1, bf16x8& hi, bf16x8& lo) {
    float f[8];
    *(f32x4*)&f[0] = v0;  *(f32x4*)&f[4] = v1;
    #pragma unroll
    for (int i = 0; i < 8; ++i) {
        unsigned u  = __float_as_uint(f[i]);
        unsigned uh = u & 0xFFFF0000u;
        float    rf = f[i] - __uint_as_float(uh);
        hi[i] = (short)(u >> 16);
        lo[i] = (short)(__float_as_uint(rf) >> 16);
    }
}

// async global->LDS, 16B per lane. LDS dest = wave-uniform base + lane*16.
__device__ __forceinline__ void gl2lds16(const void* g, void* l) {
    __builtin_amdgcn_global_load_lds(
        (const __attribute__((address_space(1))) unsigned int*)g,
        (__attribute__((address_space(3))) unsigned int*)l,
        16, 0, 0);
}

// ---------------- W pre-pack: fragment-ordered bf16 hi/lo (1 MB in d_ws) -----
// Layout: [c 0..127][t 0..3][p hi=0/lo=1][lane 0..63] x 16B.
// Wp[((c*4+t)*2+p)*512 + lane*8 .. +7] = split of W[t*16+(lane&15)][c*32+(lane>>4)*8 + 0..7]
__global__ __launch_bounds__(256) void pack_w_kernel(
    const float* __restrict__ W, short* __restrict__ Wp)
{
    const int c    = blockIdx.x;          // K chunk of 32
    const int tid  = threadIdx.x;
    const int t    = tid >> 6;
    const int lane = tid & 63;
    const int r16  = lane & 15;
    const int koct = lane >> 4;
    const float* src = W + (size_t)(t * 16 + r16) * DDIM + c * 32 + koct * 8;
    f32x4 b0 = *(const f32x4*)src;
    f32x4 b1 = *(const f32x4*)(src + 4);
    bf16x8 hi, lo;
    split8(b0, b1, hi, lo);
    short* d = Wp + ((size_t)(c * 4 + t) * 2) * 512 + lane * 8;
    *(bf16x8*)d         = hi;
    *(bf16x8*)(d + 512) = lo;
}

// ---------------- main kernel: 4 consumer waves + 4 producer waves ----------
// LDS ring: 4 buffers x 16KB, buffer = [quarter h][row 0..31][128B], row-chunk
// stored XOR-swizzled: LDS[r][cb] = x[r][cb ^ ((r&7)<<4)] (byte offsets).
__global__ __launch_bounds__(512, 4) void topk_gate_kernel(
    const float* __restrict__ x, const short* __restrict__ Wp,
    const float* __restrict__ W, float* __restrict__ out)
{
    __shared__ __align__(16) char sraw[4 * 16384];
    __shared__ int    top_i[TM * 2];
    __shared__ float  top_w[TM * 2];
    __shared__ int    nflag;
    __shared__ int    flist[TM];
    __shared__ double lgd[NEXP];
    __shared__ int    rbi[2];
    __shared__ float  rbw[2];

    const int tid  = threadIdx.x;
    const int lane = tid & 63;
    const int w    = tid >> 6;            // wave 0..7: 0-3 consumers, 4-7 producers
    const int block_tok = blockIdx.x * TM;

    if (w >= 4) {
        // ---------------- producer: stage x with counted vmcnt ----------------
        const int p  = w - 4;             // quarter 0..3
        // lane -> (row-within-8 = lane>>3, 16B-slot = lane&7), source pre-swizzled
        const int sw = (((lane & 7) ^ (lane >> 3)) << 4);
        const char* s0 = (const char*)x
            + (size_t)(block_tok + (lane >> 3)) * (DDIM * 4)   // row base (q adds 8 rows)
            + p * (KQ * 4)                                     // quarter col start (bytes)
            + sw;
        char* const dq = sraw + (p << 12);

#define STAGE(S) do {                                                        \
        char* _d = dq + (((S) & 3) << 14);                                   \
        const char* _s = s0 + (size_t)(S) * (BKQ * 4);                       \
        gl2lds16(_s,                  _d);                                   \
        gl2lds16(_s + 8  * 16384UL,   _d + 1024);                            \
        gl2lds16(_s + 16 * 16384UL,   _d + 2048);                            \
        gl2lds16(_s + 24 * 16384UL,   _d + 3072);                            \
    } while (0)

        STAGE(0); STAGE(1); STAGE(2);
        asm volatile("s_waitcnt vmcnt(8)" ::: "memory");   // step 0 landed
        __builtin_amdgcn_s_barrier();                      // barrier #1
        #pragma unroll 4
        for (int s = 0; s < NSTEP - 3; ++s) {              // s = 0..28
            STAGE(s + 3);
            asm volatile("s_waitcnt vmcnt(8)" ::: "memory"); // step s+1 landed
            __builtin_amdgcn_s_barrier();
        }
        asm volatile("s_waitcnt vmcnt(4)" ::: "memory");   // step 30 landed
        __builtin_amdgcn_s_barrier();
        asm volatile("s_waitcnt vmcnt(0)" ::: "memory");   // step 31 landed
        __builtin_amdgcn_s_barrier();
        __builtin_amdgcn_s_barrier();                      // barrier #33
#undef STAGE
    } else {
        // ---------------- consumer: MFMA over its K quarter -------------------
        const int h    = w;               // quarter 0..3
        const int r16  = lane & 15;
        const int koct = lane >> 4;
        const int q4   = (lane & 7) << 4; // read-side XOR

        f32x4 acc[2][4];
        #pragma unroll
        for (int tt = 0; tt < 2; ++tt)
            #pragma unroll
            for (int t = 0; t < 4; ++t) acc[tt][t] = (f32x4){0.f, 0.f, 0.f, 0.f};

        __syncthreads();                                   // barrier #1
        #pragma unroll 4
        for (int s = 0; s < NSTEP; ++s) {
            const char* bbase = sraw + ((s & 3) << 14) + (h << 12);
            bf16x8 ah[2], al[2];
            #pragma unroll
            for (int tt = 0; tt < 2; ++tt) {
                const char* xb = bbase + ((tt * 16 + r16) << 7);
                f32x4 a0 = *(const f32x4*)(xb + ((koct * 32)      ^ q4));
                f32x4 a1 = *(const f32x4*)(xb + ((koct * 32 + 16) ^ q4));
                split8(a0, a1, ah[tt], al[tt]);
            }
            const int cg = h * NSTEP + s;                  // global K chunk 0..127
            #pragma unroll
            for (int t = 0; t < 4; ++t) {
                const short* wb = Wp + ((size_t)(cg * 4 + t) * 2) * 512 + lane * 8;
                bf16x8 bh = *(const bf16x8*)wb;
                bf16x8 bl = *(const bf16x8*)(wb + 512);
                #pragma unroll
                for (int tt = 0; tt < 2; ++tt) {
                    acc[tt][t] = __builtin_amdgcn_mfma_f32_16x16x32_bf16(ah[tt], bh, acc[tt][t], 0, 0, 0);
                    acc[tt][t] = __builtin_amdgcn_mfma_f32_16x16x32_bf16(ah[tt], bl, acc[tt][t], 0, 0, 0);
                    acc[tt][t] = __builtin_amdgcn_mfma_f32_16x16x32_bf16(al[tt], bh, acc[tt][t], 0, 0, 0);
                }
            }
            __syncthreads();
        }
        // logits -> LDS (aliases ring buffers 0-2; all staging/reads done)
        float* Lg = (float*)sraw;         // [4][32][LSTR]
        #pragma unroll
        for (int tt = 0; tt < 2; ++tt)
            #pragma unroll
            for (int t = 0; t < 4; ++t)
                #pragma unroll
                for (int r = 0; r < 4; ++r)
                    Lg[(h * TM + tt * 16 + koct * 4 + r) * LSTR + t * 16 + r16] = acc[tt][t][r];
    }

    if (tid == 0) nflag = 0;
    __syncthreads();

    float* Lg = (float*)sraw;
    // ---- combine 4 quarters: 512 threads x (1 token, 4 experts) ----
    {
        const int tok = tid >> 4;
        const int e4  = (tid & 15) * 4;
        float4 s0 = *(float4*)&Lg[(0 * TM + tok) * LSTR + e4];
        #pragma unroll
        for (int qq = 1; qq < 4; ++qq) {
            float4 v = *(float4*)&Lg[(qq * TM + tok) * LSTR + e4];
            s0.x += v.x; s0.y += v.y; s0.z += v.z; s0.w += v.w;
        }
        *(float4*)&Lg[tok * LSTR + e4] = s0;
    }
    __syncthreads();

    // ---- top-3 scan + 2-way softmax + near-tie flagging ----
    if (tid < TM) {
        float m1 = -INFINITY, m2 = -INFINITY, m3 = -INFINITY;
        int i1 = 0, i2 = 0;
        for (int e = 0; e < NEXP; ++e) {
            float v = Lg[tid * LSTR + e];
            if (v > m1)      { m3 = m2; m2 = m1; i2 = i1; m1 = v; i1 = e; }
            else if (v > m2) { m3 = m2; m2 = v; i2 = e; }
            else if (v > m3) { m3 = v; }
        }
        float d  = expf(m2 - m1);
        float rn = 1.0f / (1.0f + d);
        top_i[tid * 2 + 0] = i1;  top_i[tid * 2 + 1] = i2;
        top_w[tid * 2 + 0] = rn;  top_w[tid * 2 + 1] = d * rn;
        float2* oi = (float2*)(out + (size_t)N_TOK * NEXP);
        oi[block_tok + tid] = make_float2((float)i1, (float)i2);
        if ((m1 - m2 < TAU) || (m2 - m3 < TAU)) {
            int pp = atomicAdd(&nflag, 1);
            flist[pp] = tid;
        }
    }
    __syncthreads();

    // ---- dense weight scatter: 32 tokens x 64 experts = 512 float4 ----
    {
        float4* ow = (float4*)(out + (size_t)block_tok * NEXP);
        const int tok = tid >> 4;
        const int e4  = (tid & 15) * 4;
        int a1 = top_i[tok * 2], a2 = top_i[tok * 2 + 1];
        float v1 = top_w[tok * 2], v2 = top_w[tok * 2 + 1];
        float4 v; float* vp = (float*)&v;
        #pragma unroll
        for (int q = 0; q < 4; ++q) {
            int e = e4 + q;
            vp[q] = (e == a1) ? v1 : ((e == a2) ? v2 : 0.0f);
        }
        ow[tid] = v;
    }
    __syncthreads();

    // ---- in-block fp64 re-resolution of flagged tokens ----
    double* red = (double*)(sraw + 40960);   // past Lg (34816B), staging dead
    const int fn = nflag;
    for (int f = 0; f < fn; ++f) {
        const int tok = block_tok + flist[f];
        {
            const int e = tid & 63, q = tid >> 6;   // q: 0..7
            const float* wr = W + (size_t)e * DDIM + q * (DDIM / 8);
            const float* xr = x + (size_t)tok * DDIM + q * (DDIM / 8);
            double pp = 0.0;
            for (int k = 0; k < DDIM / 8; k += 4) {
                float4 wv = *(const float4*)(wr + k);
                float4 xv = *(const float4*)(xr + k);
                pp += (double)xv.x * (double)wv.x;
                pp += (double)xv.y * (double)wv.y;
                pp += (double)xv.z * (double)wv.z;
                pp += (double)xv.w * (double)wv.w;
            }
            red[tid] = pp;
        }
        __syncthreads();
        if (tid < 64) {
            double s = 0.0;
            #pragma unroll
            for (int j = 0; j < 8; ++j) s += red[tid + 64 * j];
            lgd[tid] = s;
        }
        __syncthreads();

        if (tid == 0) {
            double m1 = -INFINITY, m2 = -INFINITY;
            int i1 = 0, i2 = 0;
            for (int ee = 0; ee < NEXP; ++ee) {
                double v = lgd[ee];
                if (v > m1)      { m2 = m1; i2 = i1; m1 = v; i1 = ee; }
                else if (v > m2) { m2 = v; i2 = ee; }
            }
            double d  = exp(m2 - m1);
            double rn = 1.0 / (1.0 + d);
            rbi[0] = i1; rbi[1] = i2;
            rbw[0] = (float)rn; rbw[1] = (float)(d * rn);
            float2* oi = (float2*)(out + (size_t)N_TOK * NEXP);
            oi[tok] = make_float2((float)i1, (float)i2);
        }
        __syncthreads();

        if (tid < 16) {
            float4 v = make_float4(0.f, 0.f, 0.f, 0.f);
            float* vp = (float*)&v;
            #pragma unroll
            for (int qq = 0; qq < 4; ++qq) {
                int ee = tid * 4 + qq;
                if (ee == rbi[0]) vp[qq] = rbw[0];
                else if (ee == rbi[1]) vp[qq] = rbw[1];
            }
            ((float4*)(out + (size_t)tok * NEXP))[tid] = v;
        }
        __syncthreads();
    }
}

extern "C" void kernel_launch(void* const* d_in, const int* in_sizes, int n_in,
                              void* d_out, int out_size, void* d_ws, size_t ws_size,
                              hipStream_t stream) {
    const float* x = (const float*)d_in[0];   // [16384, 4096] fp32
    const float* W = (const float*)d_in[1];   // [64, 4096] fp32
    float* out = (float*)d_out;               // weights [16384*64] then indices [16384*2]
    short* Wp  = (short*)d_ws;                // 1 MB packed W (bf16 hi/lo fragments)
    (void)in_sizes; (void)n_in; (void)ws_size; (void)out_size;

    hipLaunchKernelGGL(pack_w_kernel, dim3(DDIM / 32), dim3(256), 0, stream, W, Wp);
    hipLaunchKernelGGL(topk_gate_kernel, dim3(N_TOK / TM), dim3(512), 0, stream,
                       x, Wp, W, out);
}

// Round 4
// 494.936 us; speedup vs baseline: 1.1768x; 1.1002x over previous
//
#include <hip/hip_runtime.h>
#include <math.h>

#define N_TOK 16384
#define DDIM  4096
#define NEXP  64
#define TM    32             // tokens per block
#define WINF  256            // f32 columns staged per row per step (1 KB burst)
#define NSTEP (DDIM / WINF)  // 16 steps
#define LSTR  68             // LDS logit row stride
#define TAU   1e-3f          // near-tie refine threshold

typedef __attribute__((ext_vector_type(8))) short bf16x8;
typedef __attribute__((ext_vector_type(4))) float f32x4;

// Split 8 consecutive fp32 into hi/lo bf16 (truncation split: x = hi + lo + eps).
__device__ __forceinline__ void split8(f32x4 v0, f32x4 v1, bf16x8& hi, bf16x8& lo) {
    float f[8];
    *(f32x4*)&f[0] = v0;  *(f32x4*)&f[4] = v1;
    #pragma unroll
    for (int i = 0; i < 8; ++i) {
        unsigned u  = __float_as_uint(f[i]);
        unsigned uh = u & 0xFFFF0000u;
        float    rf = f[i] - __uint_as_float(uh);
        hi[i] = (short)(u >> 16);
        lo[i] = (short)(__float_as_uint(rf) >> 16);
    }
}

// async global->LDS, 16B per lane; LDS dest = wave-uniform base + lane*16.
__device__ __forceinline__ void gl2lds16(const void* g, void* l) {
    __builtin_amdgcn_global_load_lds(
        (const __attribute__((address_space(1))) unsigned int*)g,
        (__attribute__((address_space(3))) unsigned int*)l,
        16, 0, 0);
}

// ---------------- W pre-pack: fragment-ordered bf16 hi/lo (1 MB in d_ws) -----
// Wp[((c*4+t)*2+p)*512 + lane*8 .. +7] = split of W[t*16+(lane&15)][c*32+(lane>>4)*8 + 0..7]
__global__ __launch_bounds__(256) void pack_w_kernel(
    const float* __restrict__ W, short* __restrict__ Wp)
{
    const int c    = blockIdx.x;          // K chunk of 32
    const int tid  = threadIdx.x;
    const int t    = tid >> 6;
    const int lane = tid & 63;
    const int r16  = lane & 15;
    const int koct = lane >> 4;
    const float* src = W + (size_t)(t * 16 + r16) * DDIM + c * 32 + koct * 8;
    f32x4 b0 = *(const f32x4*)src;
    f32x4 b1 = *(const f32x4*)(src + 4);
    bf16x8 hi, lo;
    split8(b0, b1, hi, lo);
    short* d = Wp + ((size_t)(c * 4 + t) * 2) * 512 + lane * 8;
    *(bf16x8*)d         = hi;
    *(bf16x8*)(d + 512) = lo;
}

// ---------------- main kernel: 4 consumer + 4 producer waves ----------------
// LDS ring: 4 step-buffers x 32 KB; buffer = [local row 0..31][1024 B window],
// bytes within a row stored XOR-swizzled: LDS[r][b] = x[r][win + (b ^ ((r&7)<<4))].
// Each gl2lds16 = one row's 1 KB window: 64 lanes x 16B CONTIGUOUS from one row
// (lane-permuted within 128B lines only) -> large DRAM bursts, the R3 fix.
__global__ __launch_bounds__(512, 2) void topk_gate_kernel(
    const float* __restrict__ x, const short* __restrict__ Wp,
    const float* __restrict__ W, float* __restrict__ out)
{
    __shared__ __align__(16) char sraw[4 * 32768];
    __shared__ int    top_i[TM * 2];
    __shared__ float  top_w[TM * 2];
    __shared__ int    nflag;
    __shared__ int    flist[TM];
    __shared__ double lgd[NEXP];
    __shared__ int    rbi[2];
    __shared__ float  rbw[2];

    const int tid  = threadIdx.x;
    const int lane = tid & 63;
    const int w    = tid >> 6;            // 0-3 consumers, 4-7 producers
    const int block_tok = blockIdx.x * TM;

    if (w >= 4) {
        // ---------------- producer: rows p*8..p*8+7, counted vmcnt ------------
        const int p = w - 4;
        // per-row source: contiguous 1 KB, pre-swizzled within 128B lines.
        // local row r = p*8+j has (r&7)==j, so mask = j<<4.
        const char* xs[8];
        #pragma unroll
        for (int j = 0; j < 8; ++j)
            xs[j] = (const char*)x
                  + (size_t)(block_tok + p * 8 + j) * (DDIM * 4)
                  + ((lane * 16) ^ (j << 4));
        const int drow = p * 8 * 1024;

#define STAGE(S) do {                                                        \
        char* _d = sraw + (((S) & 3) << 15) + drow;                          \
        const size_t _o = (size_t)(S) * 1024;                                \
        _Pragma("unroll")                                                    \
        for (int j = 0; j < 8; ++j)                                          \
            gl2lds16(xs[j] + _o, _d + j * 1024);                             \
    } while (0)

        STAGE(0); STAGE(1); STAGE(2);                      // 24 outstanding
        asm volatile("s_waitcnt vmcnt(16)" ::: "memory");  // step 0 landed
        __builtin_amdgcn_s_barrier();                      // barrier #1
        #pragma unroll 1
        for (int s = 0; s < NSTEP - 3; ++s) {              // s = 0..12
            STAGE(s + 3);
            asm volatile("s_waitcnt vmcnt(16)" ::: "memory"); // step s+1 landed
            __builtin_amdgcn_s_barrier();                  // barrier #s+2
        }
        asm volatile("s_waitcnt vmcnt(8)" ::: "memory");   // step 14 landed
        __builtin_amdgcn_s_barrier();                      // barrier #15
        asm volatile("s_waitcnt vmcnt(0)" ::: "memory");   // step 15 landed
        __builtin_amdgcn_s_barrier();                      // barrier #16
        __builtin_amdgcn_s_barrier();                      // barrier #17
#undef STAGE
    } else {
        // ---------------- consumer: K-chunks cg ≡ {2h,2h+1} (mod 8) ----------
        const int h    = w;
        const int r16  = lane & 15;
        const int koct = lane >> 4;
        const int m    = (r16 & 7) << 4;   // read-side XOR (== row&7 of srow)

        f32x4 acc[2][4];
        #pragma unroll
        for (int tt = 0; tt < 2; ++tt)
            #pragma unroll
            for (int t = 0; t < 4; ++t) acc[tt][t] = (f32x4){0.f, 0.f, 0.f, 0.f};

        __syncthreads();                                   // barrier #1
        #pragma unroll 2
        for (int s = 0; s < NSTEP; ++s) {
            const char* buf = sraw + ((s & 3) << 15);
            #pragma unroll
            for (int cc = 0; cc < 2; ++cc) {
                const int c  = h * 2 + cc;                 // chunk in window 0..7
                const int cg = s * 8 + c;                  // global K chunk 0..127
                const int o0 = c * 128 + koct * 32;
                bf16x8 ah[2], al[2];
                #pragma unroll
                for (int tt = 0; tt < 2; ++tt) {
                    const char* xb = buf + ((tt * 16 + r16) << 10);
                    f32x4 a0 = *(const f32x4*)(xb + (o0 ^ m));
                    f32x4 a1 = *(const f32x4*)(xb + ((o0 + 16) ^ m));
                    split8(a0, a1, ah[tt], al[tt]);
                }
                #pragma unroll
                for (int t = 0; t < 4; ++t) {
                    const short* wb = Wp + ((size_t)(cg * 4 + t) * 2) * 512 + lane * 8;
                    bf16x8 bh = *(const bf16x8*)wb;
                    bf16x8 bl = *(const bf16x8*)(wb + 512);
                    #pragma unroll
                    for (int tt = 0; tt < 2; ++tt) {
                        acc[tt][t] = __builtin_amdgcn_mfma_f32_16x16x32_bf16(ah[tt], bh, acc[tt][t], 0, 0, 0);
                        acc[tt][t] = __builtin_amdgcn_mfma_f32_16x16x32_bf16(ah[tt], bl, acc[tt][t], 0, 0, 0);
                        acc[tt][t] = __builtin_amdgcn_mfma_f32_16x16x32_bf16(al[tt], bh, acc[tt][t], 0, 0, 0);
                    }
                }
            }
            __syncthreads();                               // barriers #2..#17
        }
        // logits -> LDS (ring dead: bufs 0-1 last consumed at steps 12/13)
        float* Lg = (float*)sraw;         // [4][32][LSTR]
        #pragma unroll
        for (int tt = 0; tt < 2; ++tt)
            #pragma unroll
            for (int t = 0; t < 4; ++t)
                #pragma unroll
                for (int r = 0; r < 4; ++r)
                    Lg[(h * TM + tt * 16 + koct * 4 + r) * LSTR + t * 16 + r16] = acc[tt][t][r];
    }

    if (tid == 0) nflag = 0;
    __syncthreads();

    float* Lg = (float*)sraw;
    // ---- combine 4 K-partitions: 512 threads x (1 token, 4 experts) ----
    {
        const int tok = tid >> 4;
        const int e4  = (tid & 15) * 4;
        float4 s0 = *(float4*)&Lg[(0 * TM + tok) * LSTR + e4];
        #pragma unroll
        for (int qq = 1; qq < 4; ++qq) {
            float4 v = *(float4*)&Lg[(qq * TM + tok) * LSTR + e4];
            s0.x += v.x; s0.y += v.y; s0.z += v.z; s0.w += v.w;
        }
        *(float4*)&Lg[tok * LSTR + e4] = s0;
    }
    __syncthreads();

    // ---- top-3 scan + 2-way softmax + near-tie flagging ----
    if (tid < TM) {
        float m1 = -INFINITY, m2 = -INFINITY, m3 = -INFINITY;
        int i1 = 0, i2 = 0;
        for (int e = 0; e < NEXP; ++e) {
            float v = Lg[tid * LSTR + e];
            if (v > m1)      { m3 = m2; m2 = m1; i2 = i1; m1 = v; i1 = e; }
            else if (v > m2) { m3 = m2; m2 = v; i2 = e; }
            else if (v > m3) { m3 = v; }
        }
        float d  = expf(m2 - m1);
        float rn = 1.0f / (1.0f + d);
        top_i[tid * 2 + 0] = i1;  top_i[tid * 2 + 1] = i2;
        top_w[tid * 2 + 0] = rn;  top_w[tid * 2 + 1] = d * rn;
        float2* oi = (float2*)(out + (size_t)N_TOK * NEXP);
        oi[block_tok + tid] = make_float2((float)i1, (float)i2);
        if ((m1 - m2 < TAU) || (m2 - m3 < TAU)) {
            int pp = atomicAdd(&nflag, 1);
            flist[pp] = tid;
        }
    }
    __syncthreads();

    // ---- dense weight scatter: 32 tokens x 64 experts = 512 float4 ----
    {
        float4* ow = (float4*)(out + (size_t)block_tok * NEXP);
        const int tok = tid >> 4;
        const int e4  = (tid & 15) * 4;
        int a1 = top_i[tok * 2], a2 = top_i[tok * 2 + 1];
        float v1 = top_w[tok * 2], v2 = top_w[tok * 2 + 1];
        float4 v; float* vp = (float*)&v;
        #pragma unroll
        for (int q = 0; q < 4; ++q) {
            int e = e4 + q;
            vp[q] = (e == a1) ? v1 : ((e == a2) ? v2 : 0.0f);
        }
        ow[tid] = v;
    }
    __syncthreads();

    // ---- in-block fp64 re-resolution of flagged tokens ----
    double* red = (double*)(sraw + 40960);   // past Lg (34816 B), ring dead
    const int fn = nflag;
    for (int f = 0; f < fn; ++f) {
        const int tok = block_tok + flist[f];
        {
            const int e = tid & 63, q = tid >> 6;   // q: 0..7
            const float* wr = W + (size_t)e * DDIM + q * (DDIM / 8);
            const float* xr = x + (size_t)tok * DDIM + q * (DDIM / 8);
            double pp = 0.0;
            for (int k = 0; k < DDIM / 8; k += 4) {
                float4 wv = *(const float4*)(wr + k);
                float4 xv = *(const float4*)(xr + k);
                pp += (double)xv.x * (double)wv.x;
                pp += (double)xv.y * (double)wv.y;
                pp += (double)xv.z * (double)wv.z;
                pp += (double)xv.w * (double)wv.w;
            }
            red[tid] = pp;
        }
        __syncthreads();
        if (tid < 64) {
            double s = 0.0;
            #pragma unroll
            for (int j = 0; j < 8; ++j) s += red[tid + 64 * j];
            lgd[tid] = s;
        }
        __syncthreads();

        if (tid == 0) {
            double m1 = -INFINITY, m2 = -INFINITY;
            int i1 = 0, i2 = 0;
            for (int ee = 0; ee < NEXP; ++ee) {
                double v = lgd[ee];
                if (v > m1)      { m2 = m1; i2 = i1; m1 = v; i1 = ee; }
                else if (v > m2) { m2 = v; i2 = ee; }
            }
            double d  = exp(m2 - m1);
            double rn = 1.0 / (1.0 + d);
            rbi[0] = i1; rbi[1] = i2;
            rbw[0] = (float)rn; rbw[1] = (float)(d * rn);
            float2* oi = (float2*)(out + (size_t)N_TOK * NEXP);
            oi[tok] = make_float2((float)i1, (float)i2);
        }
        __syncthreads();

        if (tid < 16) {
            float4 v = make_float4(0.f, 0.f, 0.f, 0.f);
            float* vp = (float*)&v;
            #pragma unroll
            for (int qq = 0; qq < 4; ++qq) {
                int ee = tid * 4 + qq;
                if (ee == rbi[0]) vp[qq] = rbw[0];
                else if (ee == rbi[1]) vp[qq] = rbw[1];
            }
            ((float4*)(out + (size_t)tok * NEXP))[tid] = v;
        }
        __syncthreads();
    }
}

extern "C" void kernel_launch(void* const* d_in, const int* in_sizes, int n_in,
                              void* d_out, int out_size, void* d_ws, size_t ws_size,
                              hipStream_t stream) {
    const float* x = (const float*)d_in[0];   // [16384, 4096] fp32
    const float* W = (const float*)d_in[1];   // [64, 4096] fp32
    float* out = (float*)d_out;               // weights [16384*64] then indices [16384*2]
    short* Wp  = (short*)d_ws;                // 1 MB packed W (bf16 hi/lo fragments)
    (void)in_sizes; (void)n_in; (void)ws_size; (void)out_size;

    hipLaunchKernelGGL(pack_w_kernel, dim3(DDIM / 32), dim3(256), 0, stream, W, Wp);
    hipLaunchKernelGGL(topk_gate_kernel, dim3(N_TOK / TM), dim3(512), 0, stream,
                       x, Wp, W, out);
}